// Round 10
// baseline (245.335 us; speedup 1.0000x reference)
//
#include <hip/hip_runtime.h>
#include <hip/hip_bf16.h>
#include <math.h>

#define N 4096
#define IN_F 256
#define OUT_F 512
#define H 8
#define D 64
#define NEG 0.2f
#define LOG2E 1.44269504f

typedef __attribute__((ext_vector_type(8))) short bf16x8;
typedef __attribute__((ext_vector_type(4))) float f32x4;

__device__ __forceinline__ float leaky(float x) { return fmaxf(x, NEG * x); }

__device__ __forceinline__ unsigned short f2bf(float x) {
    union { float f; unsigned u; } v; v.f = x;
    unsigned r = v.u + 0x7fff + ((v.u >> 16) & 1);  // RNE
    return (unsigned short)(r >> 16);
}

// pack two f32 -> u32 of 2x bf16 (lo=a, hi=b) via compiler intrinsic (RNE).
__device__ __forceinline__ unsigned pk_bf16(float a, float b) {
    __hip_bfloat162 h2 = __float22bfloat162_rn(float2{a, b});
    union { __hip_bfloat162 h; unsigned u; } u; u.h = h2;
    return u.u;
}

// monotone float<->uint map for atomicMax-based float max
__device__ __forceinline__ unsigned fmap(float x) {
    union { float f; unsigned u; } v; v.f = x;
    return (v.u & 0x80000000u) ? ~v.u : (v.u | 0x80000000u);
}
__device__ __forceinline__ float funmap(unsigned m) {
    union { float f; unsigned u; } v;
    v.u = (m & 0x80000000u) ? (m & 0x7fffffffu) : ~m;
    return v.f;
}

// async 16B global->LDS DMA
__device__ __forceinline__ void dma16(const void* g, void* l) {
    __builtin_amdgcn_global_load_lds((const __attribute__((address_space(1))) void*)g,
                                     (__attribute__((address_space(3))) void*)l, 16, 0, 0);
}

// ---- K1: h = inp @ W^T per (i-tile, head). Unchanged.
__global__ __launch_bounds__(256) void k_gemm(const float* __restrict__ inp,
                                              const float* __restrict__ W,
                                              const float* __restrict__ a_left,
                                              unsigned short* __restrict__ hbT,
                                              float* __restrict__ s,
                                              unsigned* __restrict__ smaxU) {
    __shared__ float As[64][69];
    __shared__ float Bs[64][69];
    __shared__ unsigned short h_st[64][72];
    __shared__ float s_red[64];

    const int t = threadIdx.x;
    const int bi = blockIdx.x;
    const int head = blockIdx.y;
    const int ty = t >> 4, tx = t & 15;
    const int lr = t >> 2;
    const int cq = (t & 3) * 16;

    float4 pa[4], pb[4];
    auto loadrk = [&](int k0) {
        const float* ip = &inp[(size_t)(bi * 64 + lr) * IN_F + k0 + cq];
        const float* wp = &W[(size_t)(head * 64 + lr) * IN_F + k0 + cq];
#pragma unroll
        for (int q = 0; q < 4; ++q) {
            pa[q] = *(const float4*)&ip[q * 4];
            pb[q] = *(const float4*)&wp[q * 4];
        }
    };
    loadrk(0);

    float acc[4][4] = {};
    for (int k0 = 0; k0 < IN_F; k0 += 64) {
        __syncthreads();
#pragma unroll
        for (int q = 0; q < 4; ++q)
#pragma unroll
            for (int j = 0; j < 4; ++j) {
                As[cq + q * 4 + j][lr] = ((const float*)&pa[q])[j];
                Bs[cq + q * 4 + j][lr] = ((const float*)&pb[q])[j];
            }
        __syncthreads();
        if (k0 + 64 < IN_F) loadrk(k0 + 64);
#pragma unroll
        for (int k = 0; k < 64; ++k) {
            float4 a4 = *(const float4*)&As[k][ty * 4];
            float4 b4 = *(const float4*)&Bs[k][tx * 4];
            float a[4] = {a4.x, a4.y, a4.z, a4.w};
            float b[4] = {b4.x, b4.y, b4.z, b4.w};
#pragma unroll
            for (int r = 0; r < 4; ++r)
#pragma unroll
                for (int c = 0; c < 4; ++c) acc[r][c] = fmaf(a[r], b[c], acc[r][c]);
        }
    }

    float aL[4];
#pragma unroll
    for (int c = 0; c < 4; ++c) aL[c] = a_left[head * D + tx * 4 + c];
#pragma unroll
    for (int r = 0; r < 4; ++r) {
        float sp = acc[r][0] * aL[0] + acc[r][1] * aL[1] + acc[r][2] * aL[2] + acc[r][3] * aL[3];
        sp += __shfl_xor(sp, 1); sp += __shfl_xor(sp, 2);
        sp += __shfl_xor(sp, 4); sp += __shfl_xor(sp, 8);
        if (tx == 0) {
            s[head * N + bi * 64 + ty * 4 + r] = sp;
            s_red[ty * 4 + r] = sp;
        }
    }
    __syncthreads();
    if (t < 64) {
        float m = s_red[t];
        for (int off = 32; off; off >>= 1) m = fmaxf(m, __shfl_down(m, off, 64));
        if (t == 0) atomicMax(&smaxU[head], fmap(m));
    }

#pragma unroll
    for (int r = 0; r < 4; ++r) {
        ushort4 v;
        v.x = f2bf(acc[r][0]); v.y = f2bf(acc[r][1]);
        v.z = f2bf(acc[r][2]); v.w = f2bf(acc[r][3]);
        *(ushort4*)&h_st[ty * 4 + r][tx * 4] = v;
    }
    __syncthreads();
    {
        const int d = t >> 2, iq = (t & 3) * 16;
        unsigned short us[16];
#pragma unroll
        for (int k = 0; k < 16; ++k) us[k] = h_st[iq + k][d];
        unsigned short* dst = &hbT[((size_t)(head * D + d)) * N + bi * 64 + iq];
#pragma unroll
        for (int q = 0; q < 4; ++q) {
            ushort4 v = {us[q * 4 + 0], us[q * 4 + 1], us[q * 4 + 2], us[q * 4 + 3]};
            *(ushort4*)&dst[q * 4] = v;
        }
    }
}

// ---- K2: per-row max of A
__global__ __launch_bounds__(256) void k_rowmax(const float* __restrict__ A,
                                                float* __restrict__ rmax) {
    int i = blockIdx.x;
    const float* row = &A[(size_t)i * N];
    float m = -1e30f;
    for (int j = threadIdx.x * 4; j < N; j += 256 * 4) {
        float4 v = *(const float4*)&row[j];
        m = fmaxf(fmaxf(fmaxf(m, v.x), fmaxf(v.y, v.z)), v.w);
    }
    for (int off = 32; off; off >>= 1) m = fmaxf(m, __shfl_down(m, off, 64));
    __shared__ float red[4];
    if ((threadIdx.x & 63) == 0) red[threadIdx.x >> 6] = m;
    __syncthreads();
    if (threadIdx.x == 0) rmax[i] = fmaxf(fmaxf(red[0], red[1]), fmaxf(red[2], red[3]));
}

// ---- K3 r10: r9 structure, CORRECTED WAIT COUNT. vmcnt retires IN ISSUE
// ORDER (m135): with per-step issue {dma(t+1) x4; As(t+2) x4}, the queue at
// step t's wait is [dma(t), As(t+1), dma(t+1), As(t+2)] = 16. r9's vmcnt(8)
// forced As(t+1) (HBM, ~900cy, only ~450cy old) -> ~400-500cy stall EVERY
// step; the depth-3 A prefetch was dead on arrival. vmcnt(12) retires
// exactly through dma(t): A-loads get true 2-step cover, DMA 1-step.
// Tail peeled: steps 60..63 use vmcnt 12/12/8/0.
__global__ __launch_bounds__(512, 4) void k_attn(const float* __restrict__ A,
                                                 const unsigned short* __restrict__ hbT,
                                                 const float* __restrict__ s,
                                                 const unsigned* __restrict__ smaxU,
                                                 const float* __restrict__ rmax,
                                                 float* __restrict__ out) {
    __shared__ unsigned short hT_st[2][16384];  // 2 bufs x (8 waves x 2048 ushorts)

    const int t = threadIdx.x;
    const int bid = blockIdx.x;
    const int hg = bid & 1;
    const int i0 = (bid >> 1) * 16;

    const int lane = t & 63, wave = t >> 6;
    const int quad = lane >> 4, li = lane & 15;
    const int wh = wave & 3, jh = wave >> 2;
    const int head = hg * 4 + wh;
    const int row = i0 + li;
    const int jb = jh * 2048;
    const int NSTEP = 2048 / 32;   // 64
    const int wbase = wave * 2048; // ushort offset of this wave's LDS region

    // per-(row,head) softmax constants (exp2 domain)
    const float sr = s[head * N + row];
    const float sI = sr * LOG2E;
    const float mb = (leaky(sr + funmap(smaxU[head])) + rmax[row]) * LOG2E;

    // Per-wave DMA sources, pre-swizzled (linear LDS dest; same XOR on read).
    const unsigned short* gH[4];
#pragma unroll
    for (int q = 0; q < 4; ++q) {
        int m = q * 64 + lane, Rloc = m >> 2, sl = m & 3;
        int grow = head * 64 + Rloc;
        int jcol = jb + ((sl ^ ((Rloc >> 1) & 3)) * 8);
        gH[q] = &hbT[(size_t)grow * N + jcol];
    }

    const float* Ap = &A[(size_t)row * N + jb + quad * 8];
    const float* sp = &s[(size_t)head * N + jb + quad * 8];

    f32x4 acc[4] = {{0,0,0,0},{0,0,0,0},{0,0,0,0},{0,0,0,0}};
    f32x4 acc_z = {0, 0, 0, 0};
    bf16x8 vones;
#pragma unroll
    for (int k = 0; k < 8; ++k) vones[k] = (short)0x3F80;  // bf16 1.0

    const int hsw = quad ^ ((li >> 1) & 3);  // read-side swizzle (per-lane const)

    auto issue_tile = [&](int buf, int jn) {
#pragma unroll
        for (int q = 0; q < 4; ++q)
            dma16(gH[q] + jn, &hT_st[buf][wbase + (q * 64 + lane) * 8]);
    };

    // A/s register pipeline: 4 sets, compile-time indexed
    float4 rA0[4], rA1[4], rS0[4], rS1[4];
#define LOAD_AS(SET, JN)                                                   \
    do {                                                                   \
        rA0[SET] = *(const float4*)&Ap[(JN)];                              \
        rA1[SET] = *(const float4*)&Ap[(JN) + 4];                          \
        rS0[SET] = *(const float4*)&sp[(JN)];                              \
        rS1[SET] = *(const float4*)&sp[(JN) + 4];                          \
    } while (0)

    auto compute_tile = [&](int buf, float4 A0, float4 A1, float4 S0, float4 S1) {
        float av[8] = {A0.x, A0.y, A0.z, A0.w, A1.x, A1.y, A1.z, A1.w};
        float sv[8] = {S0.x, S0.y, S0.z, S0.w, S1.x, S1.y, S1.z, S1.w};
        union { bf16x8 v; unsigned u[4]; } P;
#pragma unroll
        for (int p = 0; p < 4; ++p) {
            float x0 = fmaf(sv[2 * p + 0], LOG2E, sI);
            float x1 = fmaf(sv[2 * p + 1], LOG2E, sI);
            float w0 = __builtin_amdgcn_exp2f(fmaxf(x0, NEG * x0) + fmaf(av[2 * p + 0], LOG2E, -mb));
            float w1 = __builtin_amdgcn_exp2f(fmaxf(x1, NEG * x1) + fmaf(av[2 * p + 1], LOG2E, -mb));
            P.u[p] = pk_bf16(w0, w1);
        }
        acc_z = __builtin_amdgcn_mfma_f32_16x16x32_bf16(P.v, vones, acc_z, 0, 0, 0);
        const unsigned short* bH = &hT_st[buf][wbase];
#pragma unroll
        for (int db = 0; db < 4; ++db) {
            const int d = db * 16 + li;
            bf16x8 hf = *(const bf16x8*)&bH[(d * 4 + hsw) * 8];
            acc[db] = __builtin_amdgcn_mfma_f32_16x16x32_bf16(P.v, hf, acc[db], 0, 0, 0);
        }
    };

#define WAIT12 asm volatile("s_waitcnt vmcnt(12)" ::: "memory")
#define WAIT8  asm volatile("s_waitcnt vmcnt(8)"  ::: "memory")
#define WAIT0  asm volatile("s_waitcnt vmcnt(0)"  ::: "memory")
#define SBAR   __builtin_amdgcn_sched_barrier(0)

    // prologue: dma(0)->buf0; As(0)->set0; As(1)->set1
    issue_tile(0, 0);
    LOAD_AS(0, 0);
    LOAD_AS(1, 32);

    // main loop: steps 0..59 (15 x unroll-4), uniform vmcnt(12)
#pragma unroll 1
    for (int itp = 0; itp < NSTEP / 4 - 1; ++itp) {
#pragma unroll
        for (int u = 0; u < 4; ++u) {
            const int t4 = itp * 4 + u;
            issue_tile((u + 1) & 1, (t4 + 1) * 32);
            {
                const int jn = (t4 + 2) * 32;
                switch ((u + 2) & 3) {  // compile-time per unrolled instance
                    case 0: LOAD_AS(0, jn); break;
                    case 1: LOAD_AS(1, jn); break;
                    case 2: LOAD_AS(2, jn); break;
                    case 3: LOAD_AS(3, jn); break;
                }
            }
            WAIT12; SBAR;
            compute_tile(u & 1, rA0[u], rA1[u], rS0[u], rS1[u]);
        }
    }
    // peeled tail: steps 60..63
    issue_tile(1, 61 * 32); LOAD_AS(2, 62 * 32);
    WAIT12; SBAR;
    compute_tile(0, rA0[0], rA1[0], rS0[0], rS1[0]);          // t=60

    issue_tile(0, 62 * 32); LOAD_AS(3, 63 * 32);
    WAIT12; SBAR;
    compute_tile(1, rA0[1], rA1[1], rS0[1], rS1[1]);          // t=61

    issue_tile(1, 63 * 32);
    WAIT8; SBAR;
    compute_tile(0, rA0[2], rA1[2], rS0[2], rS1[2]);          // t=62

    WAIT0; SBAR;
    compute_tile(1, rA0[3], rA1[3], rS0[3], rS1[3]);          // t=63

#undef LOAD_AS
#undef WAIT12
#undef WAIT8
#undef WAIT0
#undef SBAR

    // cross-j-half reduce via LDS (stride 21 floats, conflict-free)
    __syncthreads();
    float* red = (float*)&hT_st[0][0];
    if (jh == 1) {
        const int base = (wh * 64 + lane) * 21;
#pragma unroll
        for (int db = 0; db < 4; ++db)
#pragma unroll
            for (int r = 0; r < 4; ++r) red[base + db * 4 + r] = acc[db][r];
#pragma unroll
        for (int r = 0; r < 4; ++r) red[base + 16 + r] = acc_z[r];
    }
    __syncthreads();
    if (jh == 0) {
        const int base = (wh * 64 + lane) * 21;
#pragma unroll
        for (int db = 0; db < 4; ++db)
#pragma unroll
            for (int r = 0; r < 4; ++r) acc[db][r] += red[base + db * 4 + r];
#pragma unroll
        for (int r = 0; r < 4; ++r) {
            const float zT = acc_z[r] + red[base + 16 + r];  // Z for row i0+quad*4+r
            const float inv = 1.0f / zT;
            float* op = &out[(size_t)(i0 + quad * 4 + r) * OUT_F + head * D];
#pragma unroll
            for (int db = 0; db < 4; ++db) op[db * 16 + li] = acc[db][r] * inv;
        }
    }
}

extern "C" void kernel_launch(void* const* d_in, const int* in_sizes, int n_in,
                              void* d_out, int out_size, void* d_ws, size_t ws_size,
                              hipStream_t stream) {
    const float* inp = (const float*)d_in[0];
    const float* A = (const float*)d_in[1];
    const float* W = (const float*)d_in[2];
    const float* a_left = (const float*)d_in[3];
    float* out = (float*)d_out;

    // ws layout: hbT (4MB) | s (128KB) | smaxU (32B) | rmax (16KB)
    unsigned short* hbT = (unsigned short*)d_ws;
    float* s = (float*)((char*)d_ws + (size_t)H * D * N * 2);
    unsigned* smaxU = (unsigned*)(s + (size_t)H * N);
    float* rmax = (float*)(smaxU + 8);

    hipMemsetAsync(smaxU, 0, 8 * sizeof(unsigned), stream);

    k_gemm<<<dim3(N / 64, H), 256, 0, stream>>>(inp, W, a_left, hbT, s, smaxU);
    k_rowmax<<<dim3(N), 256, 0, stream>>>(A, rmax);
    k_attn<<<dim3((N / 16) * 2), 512, 0, stream>>>(A, hbT, s, smaxU, rmax, out);
}